// Round 1
// baseline (104.152 us; speedup 1.0000x reference)
//
#include <hip/hip_runtime.h>

// NegativeSelection: score[i] = max(min_j ||x_i - s_j|| - 0.1, 0)
// N=16384, M=8192, D=128, fp32 in/out.
//
// Strategy: d2 = a2 + b2 - 2*dot. dot via fp16 MFMA (32x32x16), A pre-negated
// so acc = C_init(b2/2) + (-x)·s = b2/2 - dot; min over j tracked per row.
// final: d2 = a2 + 2*min, score = max(sqrt(max(d2,0)) - 0.1, 0).
//
// ws layout: Aws fp16 [N*128] (4 MB, tiled [tile][k8][row][8], NEGATED)
//            Bws fp16 [M*128] (2 MB, same tiling)
//            b2h  f32 [M]     (0.5*rownorm² of self)
//            Pmin f32 [N*8]   (partial mins: 4 slices × 2 col-waves)
// total ~6.8 MB.

using half_t = _Float16;
typedef _Float16 half8 __attribute__((ext_vector_type(8)));
typedef float floatx16 __attribute__((ext_vector_type(16)));

#define TILE_ELEMS (128 * 128)

__device__ __forceinline__ void async_load16(const void* g, void* l) {
    __builtin_amdgcn_global_load_lds(
        (const __attribute__((address_space(1))) void*)g,
        (__attribute__((address_space(3))) void*)l, 16, 0, 0);
}

// One block per 128x128 tile. Converts fp32 -> fp16 into tiled layout
// [k8][row][8] (chunk c = k8*128+row stored at element c*8). A is negated.
// For B tiles also computes b2h = 0.5 * sum(row^2).
__global__ __launch_bounds__(256) void prep_kernel(
    const float* __restrict__ x, const float* __restrict__ self,
    half_t* __restrict__ Aws, half_t* __restrict__ Bws,
    float* __restrict__ b2h, int Atiles)
{
    __shared__ float part[256];
    int tile = blockIdx.x;
    int tid  = threadIdx.x;
    bool isB = tile >= Atiles;
    int bt   = tile - Atiles;
    const float* src = isB ? (self + (size_t)bt * TILE_ELEMS)
                           : (x    + (size_t)tile * TILE_ELEMS);
    half_t* dst = isB ? (Bws + (size_t)bt * TILE_ELEMS)
                      : (Aws + (size_t)tile * TILE_ELEMS);
    float sgn = isB ? 1.f : -1.f;

    int rowt = tid & 127;       // this thread's row (constant across i)
    int k8b  = tid >> 7;        // 0 or 1
    float ss = 0.f;
    #pragma unroll
    for (int i = 0; i < 8; ++i) {
        int k8 = i * 2 + k8b;
        const float4* p = (const float4*)(src + rowt * 128 + k8 * 8);
        float4 f0 = p[0];
        float4 f1 = p[1];
        half8 h;
        h[0] = (half_t)(sgn * f0.x); h[1] = (half_t)(sgn * f0.y);
        h[2] = (half_t)(sgn * f0.z); h[3] = (half_t)(sgn * f0.w);
        h[4] = (half_t)(sgn * f1.x); h[5] = (half_t)(sgn * f1.y);
        h[6] = (half_t)(sgn * f1.z); h[7] = (half_t)(sgn * f1.w);
        *(half8*)(dst + (size_t)(i * 256 + tid) * 8) = h;  // identity: coalesced
        ss += f0.x*f0.x + f0.y*f0.y + f0.z*f0.z + f0.w*f0.w;
        ss += f1.x*f1.x + f1.y*f1.y + f1.z*f1.z + f1.w*f1.w;
    }
    if (isB) {
        part[tid] = ss;
        __syncthreads();
        if (tid < 128)
            b2h[bt * 128 + tid] = 0.5f * (part[tid] + part[tid + 128]);
    }
}

// Grid: (N/128 row-blocks, 4 M-slices). Block 256 = 4 waves in 2x2.
// Wave (wr,wc) computes rows wr*64..+64 x cols wc*64..+64 per B tile.
// A fragments in registers for the whole block; B staged via global_load_lds.
__global__ __launch_bounds__(256, 2) void min_gemm_kernel(
    const half_t* __restrict__ Aws, const half_t* __restrict__ Bws,
    const float* __restrict__ b2h, float* __restrict__ Pmin,
    int Mslice)
{
    __shared__ half_t Bsh[TILE_ELEMS];  // 32 KB, layout [k8][row][8]

    int tid  = threadIdx.x;
    int lane = tid & 63;
    int wid  = tid >> 6;
    int wr   = wid >> 1, wc = wid & 1;
    int ln31 = lane & 31, lh = lane >> 5;

    // A fragments: rows wr*64 + rt*32 + ln31, k = k8*8.., held in regs.
    const half_t* Atile = Aws + (size_t)blockIdx.x * TILE_ELEMS;
    half8 areg[2][8];
    #pragma unroll
    for (int rt = 0; rt < 2; ++rt)
        #pragma unroll
        for (int ki = 0; ki < 8; ++ki) {
            int k8  = ki * 2 + lh;
            int row = wr * 64 + rt * 32 + ln31;
            areg[rt][ki] = *(const half8*)(Atile + (size_t)(k8 * 128 + row) * 8);
        }

    float minacc[2][16];
    #pragma unroll
    for (int rt = 0; rt < 2; ++rt)
        #pragma unroll
        for (int r = 0; r < 16; ++r) minacc[rt][r] = 1e30f;

    int iters = Mslice >> 7;
    int s = blockIdx.y;

    for (int it = 0; it < iters; ++it) {
        const half_t* Bt = Bws + (size_t)(s * iters + it) * TILE_ELEMS;
        __syncthreads();  // LDS free (previous iter's reads done)
        #pragma unroll
        for (int j = 0; j < 8; ++j) {
            int seg = wid * 8 + j;                 // 0..31, each 1 KB
            async_load16(Bt + (size_t)(seg * 64 + lane) * 8,
                         Bsh + (size_t)seg * 512);
        }
        __syncthreads();  // loads landed

        int colbase = s * Mslice + it * 128 + wc * 64 + ln31;
        float b2v0 = b2h[colbase];
        float b2v1 = b2h[colbase + 32];

        floatx16 acc[2][2];
        #pragma unroll
        for (int r = 0; r < 16; ++r) {
            acc[0][0][r] = b2v0; acc[0][1][r] = b2v1;
            acc[1][0][r] = b2v0; acc[1][1][r] = b2v1;
        }

        #pragma unroll
        for (int ki = 0; ki < 8; ++ki) {
            int k8 = ki * 2 + lh;
            half8 bf0 = *(const half8*)(Bsh + (size_t)(k8 * 128 + wc * 64 + ln31) * 8);
            half8 bf1 = *(const half8*)(Bsh + (size_t)(k8 * 128 + wc * 64 + 32 + ln31) * 8);
            acc[0][0] = __builtin_amdgcn_mfma_f32_32x32x16_f16(areg[0][ki], bf0, acc[0][0], 0, 0, 0);
            acc[0][1] = __builtin_amdgcn_mfma_f32_32x32x16_f16(areg[0][ki], bf1, acc[0][1], 0, 0, 0);
            acc[1][0] = __builtin_amdgcn_mfma_f32_32x32x16_f16(areg[1][ki], bf0, acc[1][0], 0, 0, 0);
            acc[1][1] = __builtin_amdgcn_mfma_f32_32x32x16_f16(areg[1][ki], bf1, acc[1][1], 0, 0, 0);
        }

        // acc = b2/2 - dot; fold into running per-row min.
        #pragma unroll
        for (int rt = 0; rt < 2; ++rt)
            #pragma unroll
            for (int r = 0; r < 16; ++r) {
                float v = fminf(acc[rt][0][r], acc[rt][1][r]);
                minacc[rt][r] = fminf(minacc[rt][r], v);
            }
    }

    // min across the 32 column-lanes; C/D row = (r&3) + 8*(r>>2) + 4*lh.
    #pragma unroll
    for (int rt = 0; rt < 2; ++rt)
        #pragma unroll
        for (int r = 0; r < 16; ++r) {
            float v = minacc[rt][r];
            #pragma unroll
            for (int m = 1; m < 32; m <<= 1)
                v = fminf(v, __shfl_xor(v, m, 64));
            if (ln31 == 0) {
                int row = blockIdx.x * 128 + wr * 64 + rt * 32
                        + (r & 3) + 8 * (r >> 2) + 4 * lh;
                Pmin[(size_t)row * 8 + s * 2 + wc] = v;
            }
        }
}

// One wave per row: a2 = |x_i|^2, min of 8 partials, sqrt/shift/clamp.
__global__ __launch_bounds__(256) void final_kernel(
    const float* __restrict__ x, const float* __restrict__ Pmin,
    float* __restrict__ out)
{
    int tid  = threadIdx.x;
    int lane = tid & 63, wid = tid >> 6;
    int row  = blockIdx.x * 4 + wid;
    float2 v = ((const float2*)(x + (size_t)row * 128))[lane];
    float ss = v.x * v.x + v.y * v.y;
    #pragma unroll
    for (int m = 1; m < 64; m <<= 1) ss += __shfl_xor(ss, m, 64);
    float p = 1e30f;
    if (lane < 8) p = Pmin[(size_t)row * 8 + lane];
    #pragma unroll
    for (int m = 1; m < 8; m <<= 1) p = fminf(p, __shfl_xor(p, m, 64));
    if (lane == 0) {
        float d2 = ss + 2.f * p;          // a2 + 2*(b2/2 - dot)
        float d  = sqrtf(fmaxf(d2, 0.f));
        out[row] = fmaxf(d - 0.1f, 0.f);
    }
}

extern "C" void kernel_launch(void* const* d_in, const int* in_sizes, int n_in,
                              void* d_out, int out_size, void* d_ws, size_t ws_size,
                              hipStream_t stream)
{
    const float* x    = (const float*)d_in[0];
    const float* self = (const float*)d_in[1];
    float* out        = (float*)d_out;

    int N = in_sizes[0] / 128;   // 16384
    int M = in_sizes[1] / 128;   // 8192
    int Atiles = N / 128;        // 128
    int Btiles = M / 128;        // 64

    char* w      = (char*)d_ws;
    half_t* Aws  = (half_t*)w;
    half_t* Bws  = Aws + (size_t)N * 128;
    float*  b2h  = (float*)(w + (size_t)(N + M) * 128 * 2);
    float*  Pmin = b2h + M;
    // ws required: 4 MB + 2 MB + 32 KB + 512 KB ≈ 6.8 MB

    prep_kernel<<<Atiles + Btiles, 256, 0, stream>>>(x, self, Aws, Bws, b2h, Atiles);

    int Mslice = M / 4;          // 2048 -> 16 iterations/block
    dim3 grid(Atiles, 4);        // 512 blocks = 2/CU
    min_gemm_kernel<<<grid, 256, 0, stream>>>(Aws, Bws, b2h, Pmin, Mslice);

    final_kernel<<<N / 4, 256, 0, stream>>>(x, Pmin, out);
}